// Round 9
// baseline (140.095 us; speedup 1.0000x reference)
//
#include <hip/hip_runtime.h>

typedef __attribute__((ext_vector_type(8))) short bh8;      // 8 bf16 (4 VGPR) MFMA operand
typedef __attribute__((ext_vector_type(4))) float fx4;      // 16x16 MFMA accumulator
typedef __attribute__((ext_vector_type(16))) float fx16;    // 32x32 MFMA accumulator
typedef __attribute__((ext_vector_type(4))) unsigned short us4;
typedef unsigned short u16;

__device__ __forceinline__ u16 f2bf(float x) {
  unsigned u = __float_as_uint(x);
  u += 0x7fffu + ((u >> 16) & 1u);   // RNE
  return (u16)(u >> 16);
}

__device__ __forceinline__ void async16(const void* g, void* l) {
  __builtin_amdgcn_global_load_lds(
      (const __attribute__((address_space(1))) void*)g,
      (__attribute__((address_space(3))) void*)l,
      16, 0, 0);
}

// ---------------------------------------------------------------- convert
__global__ __launch_bounds__(256) void k_convert(
    const float* __restrict__ q, const float* __restrict__ k, const float* __restrict__ v,
    const float* __restrict__ wq, const float* __restrict__ wk,
    const float* __restrict__ wv, const float* __restrict__ wo,
    u16* __restrict__ dst) {
  size_t gid = (size_t)blockIdx.x * 256 + threadIdx.x;   // group of 4 elements
  size_t e4 = gid * 4;
  const float* src; size_t off;
  if (e4 < 4194304)        { src = q;  off = e4; }
  else if (e4 < 8388608)   { src = k;  off = e4 - 4194304; }
  else if (e4 < 12582912)  { src = v;  off = e4 - 8388608; }
  else if (e4 < 13631488)  { src = wq; off = e4 - 12582912; }
  else if (e4 < 14680064)  { src = wk; off = e4 - 13631488; }
  else if (e4 < 15728640)  { src = wv; off = e4 - 14680064; }
  else                     { src = wo; off = e4 - 15728640; }
  float4 f = *(const float4*)(src + off);
  us4 o; o.x = f2bf(f.x); o.y = f2bf(f.y); o.z = f2bf(f.z); o.w = f2bf(f.w);
  *(us4*)(dst + e4) = o;
}

// ---------------------------------------------------------------- GEMM (verified; scl in epilogue)
__device__ __forceinline__ void gemm_stage(const u16* __restrict__ A, const u16* __restrict__ B,
                                           char* lds, int bufbase, int m0, int n0, int kt, int tid) {
  int wb16 = (tid & 0xC0) * 16;   // wave-uniform part of dest
  #pragma unroll
  for (int i = 0; i < 2; ++i) {
    int cl = i * 256 + tid;
    int row = cl >> 2, ch = cl & 3;
    int sch = ch ^ (row & 3);
    const char* ga = (const char*)(A + (size_t)(m0 + row) * 1024 + kt * 32) + sch * 16;
    async16(ga, lds + bufbase + i * 4096 + wb16);
    const char* gb = (const char*)(B + (size_t)(n0 + row) * 1024 + kt * 32) + sch * 16;
    async16(gb, lds + bufbase + 8192 + i * 4096 + wb16);
  }
}

__device__ __forceinline__ void gemm_core(const u16* __restrict__ A, const u16* __restrict__ Bw,
                                          const float* __restrict__ bias, void* Cout, int mode,
                                          float scl, char* lds) {
  int tid = threadIdx.x;
  int lane = tid & 63, w = tid >> 6, g = lane >> 4, cc = lane & 15;
  int wr = w >> 1, wc = w & 1;
  int m0 = blockIdx.y * 128, n0 = blockIdx.x * 128;
  fx4 acc[4][4] = {};
  gemm_stage(A, Bw, lds, 0, m0, n0, 0, tid);
  for (int kt = 0; kt < 32; ++kt) {
    __syncthreads();   // staged tile kt ready; all waves done with buf[(kt+1)&1]
    if (kt + 1 < 32) gemm_stage(A, Bw, lds, ((kt + 1) & 1) * 16384, m0, n0, kt + 1, tid);
    const char* bA = lds + (kt & 1) * 16384;
    const char* bB = bA + 8192;
    bh8 af[4], bf[4];
    #pragma unroll
    for (int mf = 0; mf < 4; ++mf) {
      int row = wr * 64 + mf * 16 + cc;
      af[mf] = *(const bh8*)(bA + row * 64 + ((g ^ (row & 3)) * 16));
    }
    #pragma unroll
    for (int nf = 0; nf < 4; ++nf) {
      int row = wc * 64 + nf * 16 + cc;
      bf[nf] = *(const bh8*)(bB + row * 64 + ((g ^ (row & 3)) * 16));
    }
    #pragma unroll
    for (int mf = 0; mf < 4; ++mf)
      #pragma unroll
      for (int nf = 0; nf < 4; ++nf)
        acc[mf][nf] = __builtin_amdgcn_mfma_f32_16x16x32_bf16(af[mf], bf[nf], acc[mf][nf], 0, 0, 0);
  }
  // epilogue: C row = m0+wr*64+mf*16+g*4+r, col = n0+wc*64+nf*16+cc
  #pragma unroll
  for (int mf = 0; mf < 4; ++mf) {
    #pragma unroll
    for (int nf = 0; nf < 4; ++nf) {
      fx4 a = acc[mf][nf];
      int row = m0 + wr * 64 + mf * 16 + g * 4;
      int col = n0 + wc * 64 + nf * 16 + cc;
      float bv = bias[col];
      if (mode == 0) {                       // bf16 row-major (x scl)
        u16* C = (u16*)Cout;
        #pragma unroll
        for (int r = 0; r < 4; ++r) C[(size_t)(row + r) * 1024 + col] = f2bf((a[r] + bv) * scl);
      } else if (mode == 1) {                // fp32 row-major (final output)
        float* C = (float*)Cout;
        #pragma unroll
        for (int r = 0; r < 4; ++r) C[(size_t)(row + r) * 1024 + col] = (a[r] + bv) * scl;
      } else {                               // transposed bf16: Vt[b*1024+col][s]
        u16* C = (u16*)Cout;
        us4 o;
        #pragma unroll
        for (int r = 0; r < 4; ++r) o[r] = f2bf((a[r] + bv) * scl);
        int bb = row >> 11;
        *(us4*)(C + (size_t)(bb * 1024 + col) * 2048 + (row & 2047)) = o;
      }
    }
  }
}

__global__ __launch_bounds__(256) void k_gemm_qkv(
    const u16* __restrict__ qb, const u16* __restrict__ kb, const u16* __restrict__ vb,
    const u16* __restrict__ wqb, const u16* __restrict__ wkb, const u16* __restrict__ wvb,
    const float* __restrict__ bq, const float* __restrict__ bk, const float* __restrict__ bv,
    u16* __restrict__ Qp, u16* __restrict__ Kp, u16* __restrict__ Vt) {
  __shared__ __align__(16) char lds[32768];
  int z = blockIdx.z;
  const u16* A = (z == 0) ? qb : (z == 1) ? kb : vb;
  const u16* B = (z == 0) ? wqb : (z == 1) ? wkb : wvb;
  const float* bias = (z == 0) ? bq : (z == 1) ? bk : bv;
  void* C = (z == 0) ? (void*)Qp : (z == 1) ? (void*)Kp : (void*)Vt;
  float scl = (z == 0) ? 0.18033688f : 1.0f;   // fold 0.125*log2(e) into Q
  gemm_core(A, B, bias, C, (z == 2) ? 2 : 0, scl, lds);
}

__global__ __launch_bounds__(256) void k_gemm_out(
    const u16* __restrict__ Ob, const u16* __restrict__ wob,
    const float* __restrict__ bo, float* __restrict__ out) {
  __shared__ __align__(16) char lds[32768];
  gemm_core(Ob, wob, bo, out, 1, 1.0f, lds);
}

// ---------------------------------------------------------------- attention
// 32x32 MFMA flash attn, KVBLK=128 (16 iters), software-pipelined PV:
// iteration t computes QK^T(t)+exp(t) while issuing PV(t-1) from V-fragments
// pre-read into registers (read BEFORE staging t+1 overwrites that buffer;
// ordered by lgkmcnt(0)+sched_barrier). Fixed-reference softmax (Q pre-scaled
// by 0.125*log2e). Sigma-permuted K staging (swap bits 2<->3 of row&15) makes
// each lane's exp outputs exactly its PV B-fragment -> zero cross-lane traffic.
// XCD-aware remap keeps each (b,h)'s K/V on one XCD's L2.
__global__ __launch_bounds__(256) void k_attn(
    const u16* __restrict__ Qp, const u16* __restrict__ Kp,
    const u16* __restrict__ Vt, u16* __restrict__ O) {
  __shared__ __align__(16) char lds[65536];   // 2 x (K 16K + V 16K)
  int tid = threadIdx.x;
  int lane = tid & 63, w = tid >> 6, ql = lane & 31, hi = lane >> 5;
  // XCD-aware remap (bijective, 512 blocks): each XCD owns 4 whole (b,h)
  int lin = blockIdx.y * 16 + blockIdx.x;
  int xcd = lin & 7, slot = lin >> 3;
  int bh = xcd * 4 + (slot >> 4), qtile = slot & 15;
  int b = bh >> 4, h = bh & 15;
  int q0 = qtile * 128 + w * 32;
  size_t qrow = (size_t)b * 2048 + q0 + ql;
  // Q B-frags (pre-scaled): slot(hi,e) = Q'[q=ql][d = ds*16 + hi*8 + e]
  bh8 qf[4];
  #pragma unroll
  for (int ds = 0; ds < 4; ++ds)
    qf[ds] = *(const bh8*)(Qp + qrow * 1024 + h * 64 + ds * 16 + hi * 8);

  // K staging: dest rows r0 + 32*i, source row sigma(dest) (swap bits 2,3 of row&15)
  int r0 = tid >> 3;
  int gr0 = (r0 & 19) | (((r0 >> 2) & 1) << 3) | (((r0 >> 3) & 1) << 2);
  int sK = (tid & 7) ^ (r0 & 7);
  const char* gK = (const char*)(Kp + (size_t)(b * 2048 + gr0) * 1024 + h * 64) + sK * 16;
  // V staging: dest rows vr0 + 16*i, 16 chunks/row (256B)
  int vr0 = tid >> 4;
  int sV = (tid & 15) ^ (vr0 & 7);
  const char* gV = (const char*)(Vt + ((size_t)(b * 1024 + h * 64 + vr0)) * 2048) + sV * 16;
  int wb16 = (tid & 0xC0) * 16;

  // fragment LDS offsets
  int x7 = ql & 7;
  int kbase = ql * 128, vbase = ql * 256;
  int kc[4], vc[8];
  #pragma unroll
  for (int ds = 0; ds < 4; ++ds) kc[ds] = ((ds * 2 + hi) ^ x7) * 16;
  #pragma unroll
  for (int ks = 0; ks < 8; ++ks) vc[ks] = ((ks * 2 + hi) ^ x7) * 16;

  float lpart = 0.f;                    // per-lane partial denominator
  fx16 ot[2] = {};                      // O^T: d = dt*32 + 4*hi + (reg&3) + 8*(reg>>2), q = ql
  bh8 pf[8];                            // Pf of tile t-1 (persisted across iterations)

  // prologue stage t=0 into buf0
  #pragma unroll
  for (int i = 0; i < 4; ++i) {
    async16(gK + i * 65536, lds + i * 4096 + wb16);
    async16(gV + i * 65536, lds + 16384 + i * 4096 + wb16);
  }
  gK += 262144; gV += 256;

  for (int t = 0; t < 16; ++t) {
    __syncthreads();
    const char* bufc = lds + ((t & 1) << 15);        // tile t (K, V)
    char* bufp = lds + (((t + 1) & 1) << 15);        // tile t-1 V; staging dest for t+1
    // read V(t-1) fragments into registers BEFORE staging t+1 overwrites bufp
    bh8 va[2][8];
    if (t) {
      #pragma unroll
      for (int dt = 0; dt < 2; ++dt)
        #pragma unroll
        for (int ks = 0; ks < 8; ++ks)
          va[dt][ks] = *(const bh8*)(bufp + 16384 + dt * 8192 + vbase + vc[ks]);
      asm volatile("s_waitcnt lgkmcnt(0)" ::: "memory");   // V-frags landed in regs
      __builtin_amdgcn_sched_barrier(0);                   // pin: reads before DMA issue
    }
    if (t + 1 < 16) {
      #pragma unroll
      for (int i = 0; i < 4; ++i) {
        async16(gK + i * 65536, bufp + i * 4096 + wb16);
        async16(gV + i * 65536, bufp + 16384 + i * 4096 + wb16);
      }
      gK += 262144; gV += 256;
    }
    // QK^T(t): st[kk][8m+e] = S[k = kk*32 + 16m + 8hi + e][q=ql]
    fx16 st[4] = {};
    __builtin_amdgcn_s_setprio(1);
    #pragma unroll
    for (int kk = 0; kk < 4; ++kk)
      #pragma unroll
      for (int ds = 0; ds < 4; ++ds)
        st[kk] = __builtin_amdgcn_mfma_f32_32x32x16_bf16(
            *(const bh8*)(bufc + kk * 4096 + kbase + kc[ds]), qf[ds], st[kk], 0, 0, 0);
    __builtin_amdgcn_s_setprio(0);
    // exp(t) -> Pf_new (VALU)  [overlaps PV(t-1) MFMA below]
    bh8 pfn[8];
    #pragma unroll
    for (int kk = 0; kk < 4; ++kk) {
      #pragma unroll
      for (int m = 0; m < 2; ++m) {
        float p[8];
        #pragma unroll
        for (int e = 0; e < 8; ++e) p[e] = __builtin_amdgcn_exp2f(st[kk][8 * m + e]);
        lpart += ((p[0] + p[1]) + (p[2] + p[3])) + ((p[4] + p[5]) + (p[6] + p[7]));
        unsigned u0, u1, u2, u3;
        asm("v_cvt_pk_bf16_f32 %0, %1, %2" : "=v"(u0) : "v"(p[0]), "v"(p[1]));
        asm("v_cvt_pk_bf16_f32 %0, %1, %2" : "=v"(u1) : "v"(p[2]), "v"(p[3]));
        asm("v_cvt_pk_bf16_f32 %0, %1, %2" : "=v"(u2) : "v"(p[4]), "v"(p[5]));
        asm("v_cvt_pk_bf16_f32 %0, %1, %2" : "=v"(u3) : "v"(p[6]), "v"(p[7]));
        union { unsigned u[4]; bh8 v; } pu;
        pu.u[0] = u0; pu.u[1] = u1; pu.u[2] = u2; pu.u[3] = u3;
        pfn[kk * 2 + m] = pu.v;
      }
    }
    // PV(t-1) from registers (MFMA pipe, overlaps exp above)
    if (t) {
      __builtin_amdgcn_s_setprio(1);
      #pragma unroll
      for (int dt = 0; dt < 2; ++dt)
        #pragma unroll
        for (int ks = 0; ks < 8; ++ks)
          ot[dt] = __builtin_amdgcn_mfma_f32_32x32x16_bf16(va[dt][ks], pf[ks], ot[dt], 0, 0, 0);
      __builtin_amdgcn_s_setprio(0);
    }
    #pragma unroll
    for (int ks = 0; ks < 8; ++ks) pf[ks] = pfn[ks];
  }
  // epilogue: PV(15) — V(15) lives in buf[1], no staging after it
  {
    const char* bV = lds + (1 << 15) + 16384;
    bh8 va[2][8];
    #pragma unroll
    for (int dt = 0; dt < 2; ++dt)
      #pragma unroll
      for (int ks = 0; ks < 8; ++ks)
        va[dt][ks] = *(const bh8*)(bV + dt * 8192 + vbase + vc[ks]);
    #pragma unroll
    for (int dt = 0; dt < 2; ++dt)
      #pragma unroll
      for (int ks = 0; ks < 8; ++ks)
        ot[dt] = __builtin_amdgcn_mfma_f32_32x32x16_bf16(va[dt][ks], pf[ks], ot[dt], 0, 0, 0);
  }
  // denominator: lane pair (ql, ql+32) sums to the full row
  float lsum = lpart + __shfl_xor(lpart, 32);
  float inv = 1.f / lsum;
  #pragma unroll
  for (int dt = 0; dt < 2; ++dt)
    #pragma unroll
    for (int j = 0; j < 4; ++j) {
      us4 o4;
      #pragma unroll
      for (int i = 0; i < 4; ++i) o4[i] = f2bf(ot[dt][4 * j + i] * inv);
      *(us4*)(O + qrow * 1024 + h * 64 + dt * 32 + j * 8 + hi * 4) = o4;
    }
}

// ---------------------------------------------------------------- launch
extern "C" void kernel_launch(void* const* d_in, const int* in_sizes, int n_in,
                              void* d_out, int out_size, void* d_ws, size_t ws_size,
                              hipStream_t stream) {
  const float* q  = (const float*)d_in[0];
  const float* k  = (const float*)d_in[1];
  const float* v  = (const float*)d_in[2];
  const float* Wq = (const float*)d_in[3];
  const float* bq = (const float*)d_in[4];
  const float* Wk = (const float*)d_in[5];
  const float* bk = (const float*)d_in[6];
  const float* Wv = (const float*)d_in[7];
  const float* bv = (const float*)d_in[8];
  const float* Wo = (const float*)d_in[9];
  const float* bo = (const float*)d_in[10];
  u16* ws  = (u16*)d_ws;
  u16* qb  = ws;               // [4096,1024] bf16
  u16* kb  = qb + 4194304;
  u16* vb  = kb + 4194304;
  u16* wqb = vb + 4194304;     // [1024,1024] bf16 each
  u16* wkb = wqb + 1048576;
  u16* wvb = wkb + 1048576;
  u16* wob = wvb + 1048576;
  u16* Qp  = wob + 1048576;    // [4096,1024] bf16 (pre-scaled by 0.125*log2e)
  u16* Kp  = Qp + 4194304;
  u16* Vt  = Kp + 4194304;     // [2048,2048] bf16 (V transposed per batch)
  u16* Ob  = qb;               // attention output aliases qb (dead by then)

  k_convert<<<dim3(16384), 256, 0, stream>>>(q, k, v, Wq, Wk, Wv, Wo, qb);
  k_gemm_qkv<<<dim3(8, 32, 3), 256, 0, stream>>>(qb, kb, vb, wqb, wkb, wvb, bq, bk, bv, Qp, Kp, Vt);
  k_attn<<<dim3(16, 32), 256, 0, stream>>>(Qp, Kp, Vt, Ob);
  k_gemm_out<<<dim3(8, 32, 1), 256, 0, stream>>>(Ob, wob, bo, (float*)d_out);
}

// Round 10
// 122.774 us; speedup vs baseline: 1.1411x; 1.1411x over previous
//
#include <hip/hip_runtime.h>

typedef __attribute__((ext_vector_type(8))) short bh8;      // 8 bf16 (4 VGPR) MFMA operand
typedef __attribute__((ext_vector_type(4))) float fx4;      // 16x16 MFMA accumulator
typedef __attribute__((ext_vector_type(16))) float fx16;    // 32x32 MFMA accumulator
typedef __attribute__((ext_vector_type(4))) unsigned short us4;
typedef unsigned short u16;

__device__ __forceinline__ u16 f2bf(float x) {
  unsigned u = __float_as_uint(x);
  u += 0x7fffu + ((u >> 16) & 1u);   // RNE
  return (u16)(u >> 16);
}

__device__ __forceinline__ void async16(const void* g, void* l) {
  __builtin_amdgcn_global_load_lds(
      (const __attribute__((address_space(1))) void*)g,
      (__attribute__((address_space(3))) void*)l,
      16, 0, 0);
}

// ---------------------------------------------------------------- convert
__global__ __launch_bounds__(256) void k_convert(
    const float* __restrict__ q, const float* __restrict__ k, const float* __restrict__ v,
    const float* __restrict__ wq, const float* __restrict__ wk,
    const float* __restrict__ wv, const float* __restrict__ wo,
    u16* __restrict__ dst) {
  size_t gid = (size_t)blockIdx.x * 256 + threadIdx.x;   // group of 4 elements
  size_t e4 = gid * 4;
  const float* src; size_t off;
  if (e4 < 4194304)        { src = q;  off = e4; }
  else if (e4 < 8388608)   { src = k;  off = e4 - 4194304; }
  else if (e4 < 12582912)  { src = v;  off = e4 - 8388608; }
  else if (e4 < 13631488)  { src = wq; off = e4 - 12582912; }
  else if (e4 < 14680064)  { src = wk; off = e4 - 13631488; }
  else if (e4 < 15728640)  { src = wv; off = e4 - 14680064; }
  else                     { src = wo; off = e4 - 15728640; }
  float4 f = *(const float4*)(src + off);
  us4 o; o.x = f2bf(f.x); o.y = f2bf(f.y); o.z = f2bf(f.z); o.w = f2bf(f.w);
  *(us4*)(dst + e4) = o;
}

// ---------------------------------------------------------------- GEMM
// Templated by BM (tile = BM x 128, BK=32). BM=128 reduces byte-exactly to the
// verified R8 structure; BM=64 doubles block count for occupancy-starved dispatches.
// LDS per buffer: A BM*64B + B 8192B; linear dest, 16B-chunk XOR-swizzle (row&3)
// applied on pre-swizzled global source and on ds_read.
template<int BM>
__device__ __forceinline__ void gemm_stageT(const u16* __restrict__ A, const u16* __restrict__ B,
                                            char* lds, int bufbase, int m0, int n0, int kt, int tid) {
  int wb16 = (tid & 0xC0) * 16;   // wave-uniform part of dest
  #pragma unroll
  for (int i = 0; i < BM / 64; ++i) {   // A: BM*4 chunks
    int cl = i * 256 + tid;
    int row = cl >> 2, ch = cl & 3;
    int sch = ch ^ (row & 3);
    const char* ga = (const char*)(A + (size_t)(m0 + row) * 1024 + kt * 32) + sch * 16;
    async16(ga, lds + bufbase + i * 4096 + wb16);
  }
  #pragma unroll
  for (int i = 0; i < 2; ++i) {         // B: 512 chunks
    int cl = i * 256 + tid;
    int row = cl >> 2, ch = cl & 3;
    int sch = ch ^ (row & 3);
    const char* gb = (const char*)(B + (size_t)(n0 + row) * 1024 + kt * 32) + sch * 16;
    async16(gb, lds + bufbase + BM * 64 + i * 4096 + wb16);
  }
}

template<int BM>
__device__ __forceinline__ void gemm_coreT(const u16* __restrict__ A, const u16* __restrict__ Bw,
                                           const float* __restrict__ bias, void* Cout, int mode,
                                           float scl, char* lds) {
  constexpr int MF = BM / 32;           // m-frags per wave (wave covers BM/2 rows)
  constexpr int BUFSZ = BM * 64 + 8192;
  int tid = threadIdx.x;
  int lane = tid & 63, w = tid >> 6, g = lane >> 4, cc = lane & 15;
  int wr = w >> 1, wc = w & 1;
  int m0 = blockIdx.y * BM, n0 = blockIdx.x * 128;
  fx4 acc[MF][4] = {};
  gemm_stageT<BM>(A, Bw, lds, 0, m0, n0, 0, tid);
  for (int kt = 0; kt < 32; ++kt) {
    __syncthreads();   // staged tile kt ready; all waves done with buf[(kt+1)&1]
    if (kt + 1 < 32) gemm_stageT<BM>(A, Bw, lds, ((kt + 1) & 1) * BUFSZ, m0, n0, kt + 1, tid);
    const char* bA = lds + (kt & 1) * BUFSZ;
    const char* bB = bA + BM * 64;
    bh8 af[MF], bf[4];
    #pragma unroll
    for (int mf = 0; mf < MF; ++mf) {
      int row = wr * (BM / 2) + mf * 16 + cc;
      af[mf] = *(const bh8*)(bA + row * 64 + ((g ^ (row & 3)) * 16));
    }
    #pragma unroll
    for (int nf = 0; nf < 4; ++nf) {
      int row = wc * 64 + nf * 16 + cc;
      bf[nf] = *(const bh8*)(bB + row * 64 + ((g ^ (row & 3)) * 16));
    }
    #pragma unroll
    for (int mf = 0; mf < MF; ++mf)
      #pragma unroll
      for (int nf = 0; nf < 4; ++nf)
        acc[mf][nf] = __builtin_amdgcn_mfma_f32_16x16x32_bf16(af[mf], bf[nf], acc[mf][nf], 0, 0, 0);
  }
  // epilogue: C row = m0+wr*(BM/2)+mf*16+g*4+r, col = n0+wc*64+nf*16+cc
  #pragma unroll
  for (int mf = 0; mf < MF; ++mf) {
    #pragma unroll
    for (int nf = 0; nf < 4; ++nf) {
      fx4 a = acc[mf][nf];
      int row = m0 + wr * (BM / 2) + mf * 16 + g * 4;
      int col = n0 + wc * 64 + nf * 16 + cc;
      float bv = bias[col];
      if (mode == 0) {                       // bf16 row-major (x scl)
        u16* C = (u16*)Cout;
        #pragma unroll
        for (int r = 0; r < 4; ++r) C[(size_t)(row + r) * 1024 + col] = f2bf((a[r] + bv) * scl);
      } else if (mode == 1) {                // fp32 row-major (final output)
        float* C = (float*)Cout;
        #pragma unroll
        for (int r = 0; r < 4; ++r) C[(size_t)(row + r) * 1024 + col] = (a[r] + bv) * scl;
      } else {                               // transposed bf16: Vt[b*1024+col][s]
        u16* C = (u16*)Cout;
        us4 o;
        #pragma unroll
        for (int r = 0; r < 4; ++r) o[r] = f2bf((a[r] + bv) * scl);
        int bb = row >> 11;
        *(us4*)(C + (size_t)(bb * 1024 + col) * 2048 + (row & 2047)) = o;
      }
    }
  }
}

__global__ __launch_bounds__(256) void k_gemm_qkv(
    const u16* __restrict__ qb, const u16* __restrict__ kb, const u16* __restrict__ vb,
    const u16* __restrict__ wqb, const u16* __restrict__ wkb, const u16* __restrict__ wvb,
    const float* __restrict__ bq, const float* __restrict__ bk, const float* __restrict__ bv,
    u16* __restrict__ Qp, u16* __restrict__ Kp, u16* __restrict__ Vt) {
  __shared__ __align__(16) char lds[32768];
  int z = blockIdx.z;
  const u16* A = (z == 0) ? qb : (z == 1) ? kb : vb;
  const u16* B = (z == 0) ? wqb : (z == 1) ? wkb : wvb;
  const float* bias = (z == 0) ? bq : (z == 1) ? bk : bv;
  void* C = (z == 0) ? (void*)Qp : (z == 1) ? (void*)Kp : (void*)Vt;
  float scl = (z == 0) ? 0.18033688f : 1.0f;   // fold 0.125*log2(e) into Q
  gemm_coreT<128>(A, B, bias, C, (z == 2) ? 2 : 0, scl, lds);
}

__global__ __launch_bounds__(256) void k_gemm_out(
    const u16* __restrict__ Ob, const u16* __restrict__ wob,
    const float* __restrict__ bo, float* __restrict__ out) {
  __shared__ __align__(16) char lds[24576];    // 2 x (A 4K + B 8K)
  gemm_coreT<64>(Ob, wob, bo, out, 1, 1.0f, lds);
}

// ---------------------------------------------------------------- attention (byte-exact R8, verified 52.2us)
// 32x32 MFMA flash attn, KVBLK=128 (16 iters). Block: one (b,h), 128 q-rows
// (4 waves x 32). XCD-aware remap (K/V L2-resident per XCD). Fixed-reference
// softmax with Q pre-scaled by 0.125*log2(e): p = exp2(st) directly.
// K staged with sigma-permuted rows (swap bits 2<->3 of row&15) so the 32x32
// C-layout hands each lane exactly its PV B-fragment k-halves: no cross-lane
// exchange at all. V tile [64 d][256B]; K tile [128 k][128B]; 16B-chunk XOR
// swizzle (row&7) on both; double-buffered, 64 KB LDS.
__global__ __launch_bounds__(256) void k_attn(
    const u16* __restrict__ Qp, const u16* __restrict__ Kp,
    const u16* __restrict__ Vt, u16* __restrict__ O) {
  __shared__ __align__(16) char lds[65536];   // 2 x (K 16K + V 16K)
  int tid = threadIdx.x;
  int lane = tid & 63, w = tid >> 6, ql = lane & 31, hi = lane >> 5;
  // XCD-aware remap (bijective, 512 blocks): each XCD owns 4 whole (b,h)
  int lin = blockIdx.y * 16 + blockIdx.x;
  int xcd = lin & 7, slot = lin >> 3;
  int bh = xcd * 4 + (slot >> 4), qtile = slot & 15;
  int b = bh >> 4, h = bh & 15;
  int q0 = qtile * 128 + w * 32;
  size_t qrow = (size_t)b * 2048 + q0 + ql;
  // Q B-frags (pre-scaled): slot(hi,e) = Q'[q=ql][d = ds*16 + hi*8 + e]
  bh8 qf[4];
  #pragma unroll
  for (int ds = 0; ds < 4; ++ds)
    qf[ds] = *(const bh8*)(Qp + qrow * 1024 + h * 64 + ds * 16 + hi * 8);

  // K staging: dest rows r0 + 32*i (r0 = tid>>3, 0..31), source row sigma(dest):
  // swap bits 2,3 within (row&15); bit4 preserved; chunk swizzle keyed on DEST row.
  int r0 = tid >> 3;
  int gr0 = (r0 & 19) | (((r0 >> 2) & 1) << 3) | (((r0 >> 3) & 1) << 2);  // &19 keeps bits 0,1,4
  int sK = (tid & 7) ^ (r0 & 7);
  const char* gK = (const char*)(Kp + (size_t)(b * 2048 + gr0) * 1024 + h * 64) + sK * 16;
  // V staging: dest rows vr0 + 16*i (vr0 = tid>>4, 0..15), 16 chunks/row (256B)
  int vr0 = tid >> 4;
  int sV = (tid & 15) ^ (vr0 & 7);
  const char* gV = (const char*)(Vt + ((size_t)(b * 1024 + h * 64 + vr0)) * 2048) + sV * 16;
  int wb16 = (tid & 0xC0) * 16;

  // fragment LDS offsets: row&7 == ql&7 for all sub-tiles (strides are mult of 8)
  int x7 = ql & 7;
  int kbase = ql * 128, vbase = ql * 256;
  int kc[4], vc[8];
  #pragma unroll
  for (int ds = 0; ds < 4; ++ds) kc[ds] = ((ds * 2 + hi) ^ x7) * 16;
  #pragma unroll
  for (int ks = 0; ks < 8; ++ks) vc[ks] = ((ks * 2 + hi) ^ x7) * 16;

  float lpart = 0.f;                    // per-lane partial denominator
  fx16 ot[2] = {};                      // O^T: d = dt*32 + 4*hi + (reg&3) + 8*(reg>>2), q = ql
  // prologue stage t=0
  #pragma unroll
  for (int i = 0; i < 4; ++i) {
    async16(gK + i * 65536, lds + i * 4096 + wb16);
    async16(gV + i * 65536, lds + 16384 + i * 4096 + wb16);
  }
  gK += 262144; gV += 256;

  for (int t = 0; t < 16; ++t) {
    __syncthreads();
    if (t + 1 < 16) {
      int bb = ((t + 1) & 1) << 15;
      #pragma unroll
      for (int i = 0; i < 4; ++i) {
        async16(gK + i * 65536, lds + bb + i * 4096 + wb16);
        async16(gV + i * 65536, lds + bb + 16384 + i * 4096 + wb16);
      }
      gK += 262144; gV += 256;
    }
    const char* bK = lds + ((t & 1) << 15);
    const char* bV = bK + 16384;
    // QK^T: st[kk][8m+e] = S[k = kk*32 + 16m + 8hi + e][q=ql]  (sigma-permuted K)
    fx16 st[4] = {};
    #pragma unroll
    for (int kk = 0; kk < 4; ++kk)
      #pragma unroll
      for (int ds = 0; ds < 4; ++ds)
        st[kk] = __builtin_amdgcn_mfma_f32_32x32x16_bf16(
            *(const bh8*)(bK + kk * 4096 + kbase + kc[ds]), qf[ds], st[kk], 0, 0, 0);
    // fixed-reference softmax: p = exp2(st); lane's 8-value groups ARE its PV B-frags
    bh8 Pf[8];
    #pragma unroll
    for (int kk = 0; kk < 4; ++kk) {
      #pragma unroll
      for (int m = 0; m < 2; ++m) {
        float p[8];
        #pragma unroll
        for (int e = 0; e < 8; ++e) p[e] = __builtin_amdgcn_exp2f(st[kk][8 * m + e]);
        lpart += ((p[0] + p[1]) + (p[2] + p[3])) + ((p[4] + p[5]) + (p[6] + p[7]));
        unsigned u0, u1, u2, u3;
        asm("v_cvt_pk_bf16_f32 %0, %1, %2" : "=v"(u0) : "v"(p[0]), "v"(p[1]));
        asm("v_cvt_pk_bf16_f32 %0, %1, %2" : "=v"(u1) : "v"(p[2]), "v"(p[3]));
        asm("v_cvt_pk_bf16_f32 %0, %1, %2" : "=v"(u2) : "v"(p[4]), "v"(p[5]));
        asm("v_cvt_pk_bf16_f32 %0, %1, %2" : "=v"(u3) : "v"(p[6]), "v"(p[7]));
        union { unsigned u[4]; bh8 v; } pu;
        pu.u[0] = u0; pu.u[1] = u1; pu.u[2] = u2; pu.u[3] = u3;
        Pf[kk * 2 + m] = pu.v;
      }
    }
    // O^T += V^T * P^T  (2 d-tiles x 8 K=16 slices)
    #pragma unroll
    for (int dt = 0; dt < 2; ++dt)
      #pragma unroll
      for (int ks = 0; ks < 8; ++ks)
        ot[dt] = __builtin_amdgcn_mfma_f32_32x32x16_bf16(
            *(const bh8*)(bV + dt * 8192 + vbase + vc[ks]), Pf[ks], ot[dt], 0, 0, 0);
  }
  // denominator: lane pair (ql, ql+32) sums to the full row
  float lsum = lpart + __shfl_xor(lpart, 32);
  float inv = 1.f / lsum;
  #pragma unroll
  for (int dt = 0; dt < 2; ++dt)
    #pragma unroll
    for (int j = 0; j < 4; ++j) {
      us4 o4;
      #pragma unroll
      for (int i = 0; i < 4; ++i) o4[i] = f2bf(ot[dt][4 * j + i] * inv);
      *(us4*)(O + qrow * 1024 + h * 64 + dt * 32 + j * 8 + hi * 4) = o4;
    }
}

// ---------------------------------------------------------------- launch
extern "C" void kernel_launch(void* const* d_in, const int* in_sizes, int n_in,
                              void* d_out, int out_size, void* d_ws, size_t ws_size,
                              hipStream_t stream) {
  const float* q  = (const float*)d_in[0];
  const float* k  = (const float*)d_in[1];
  const float* v  = (const float*)d_in[2];
  const float* Wq = (const float*)d_in[3];
  const float* bq = (const float*)d_in[4];
  const float* Wk = (const float*)d_in[5];
  const float* bk = (const float*)d_in[6];
  const float* Wv = (const float*)d_in[7];
  const float* bv = (const float*)d_in[8];
  const float* Wo = (const float*)d_in[9];
  const float* bo = (const float*)d_in[10];
  u16* ws  = (u16*)d_ws;
  u16* qb  = ws;               // [4096,1024] bf16
  u16* kb  = qb + 4194304;
  u16* vb  = kb + 4194304;
  u16* wqb = vb + 4194304;     // [1024,1024] bf16 each
  u16* wkb = wqb + 1048576;
  u16* wvb = wkb + 1048576;
  u16* wob = wvb + 1048576;
  u16* Qp  = wob + 1048576;    // [4096,1024] bf16 (pre-scaled by 0.125*log2e)
  u16* Kp  = Qp + 4194304;
  u16* Vt  = Kp + 4194304;     // [2048,2048] bf16 (V transposed per batch)
  u16* Ob  = qb;               // attention output aliases qb (dead by then)

  k_convert<<<dim3(16384), 256, 0, stream>>>(q, k, v, Wq, Wk, Wv, Wo, qb);
  k_gemm_qkv<<<dim3(8, 32, 3), 256, 0, stream>>>(qb, kb, vb, wqb, wkb, wvb, bq, bk, bv, Qp, Kp, Vt);
  k_attn<<<dim3(16, 32), 256, 0, stream>>>(Qp, Kp, Vt, Ob);
  k_gemm_out<<<dim3(8, 64), 256, 0, stream>>>(Ob, wob, bo, (float*)d_out);
}